// Round 17
// baseline (501.011 us; speedup 1.0000x reference)
//
#include <hip/hip_runtime.h>
#include <hip/hip_bf16.h>

// Linear recurrence h_t = x_t@W + h_{t-1}@R, parallel scan, chunk C=8.
// R17 = R15 structure + (from R16) fix0 R-frag register cache and k_local
// dstep d1-drop; R16's fused scattered out-write REVERTED (it caused
// write-allocate RMW: FETCH 94->311 MB, HBM-bound). Full-row coalesced
// writes via LDS (write_bt) are mandatory on gfx950.

typedef float f32x4 __attribute__((ext_vector_type(4)));
typedef __bf16 bf16x8 __attribute__((ext_vector_type(8)));

#define TDIM 2048L
#define UDIM 512L
#define ST32 16384L     // elems per [32,512] state
#define ST64 32768L     // elems per [64,512] tile
#define TS 262144L      // elems per frag term
#define FE 786432L      // elems per 3-term frag matrix
#define PP 520          // padded plane row stride (bf16 elems)

__device__ __forceinline__ f32x4 mfma16(bf16x8 a, bf16x8 b, f32x4 c) {
  return __builtin_amdgcn_mfma_f32_16x16x32_bf16(a, b, c, 0, 0, 0);
}

// fp32 [32][512] swizzle (staging for sq/pair/down)
__device__ __forceinline__ int hidx(int row, int col) {
  return row * 512 + (col ^ ((row & 7) << 3));
}

__device__ __forceinline__ void pack8(const f32x4& v0, const f32x4& v1,
                                      bf16x8& hv, bf16x8& lv) {
#pragma unroll
  for (int j = 0; j < 4; ++j) {
    const float a = v0[j];
    const __bf16 ha = (__bf16)a;
    hv[j] = ha; lv[j] = (__bf16)(a - (float)ha);
    const float b = v1[j];
    const __bf16 hb = (__bf16)b;
    hv[j + 4] = hb; lv[j + 4] = (__bf16)(b - (float)hb);
  }
}

// ---- M=32 pair-plane helpers (stride PP, blockDim-stride loops) -----------

__device__ __forceinline__ void stage32p(const float* __restrict__ src,
                                         long pitch, __bf16* Phi, __bf16* Plo) {
  for (int i = threadIdx.x; i < 2048; i += blockDim.x) {
    const int row = i >> 6, cb = i & 63;
    const float* p = src + (long)row * pitch + cb * 8;
    bf16x8 hv, lv;
    pack8(*(const f32x4*)p, *(const f32x4*)(p + 4), hv, lv);
    const int o = row * PP + cb * 8;
    *(bf16x8*)(Phi + o) = hv;
    *(bf16x8*)(Plo + o) = lv;
  }
}

// planes -> out[B,T,U] at time t (fp32 = hi+lo), full-row coalesced stores
__device__ __forceinline__ void write_bt(const __bf16* Phi, const __bf16* Plo,
                                         float* out, long t) {
  for (int i = threadIdx.x; i < 2048; i += blockDim.x) {
    const int row = i >> 6, cb = i & 63;
    const int o = row * PP + cb * 8;
    const bf16x8 hv = *(const bf16x8*)(Phi + o);
    const bf16x8 lv = *(const bf16x8*)(Plo + o);
    f32x4 o0, o1;
#pragma unroll
    for (int j = 0; j < 4; ++j) {
      o0[j] = (float)hv[j] + (float)lv[j];
      o1[j] = (float)hv[j + 4] + (float)lv[j + 4];
    }
    float* dst = out + (long)row * (TDIM * UDIM) + t * UDIM + cb * 8;
    *(f32x4*)dst = o0;
    *(f32x4*)(dst + 4) = o1;
  }
}

__device__ __forceinline__ void write_flat(const __bf16* Phi, const __bf16* Plo,
                                           float* dst) {
  for (int i = threadIdx.x; i < 2048; i += blockDim.x) {
    const int row = i >> 6, cb = i & 63;
    const int o = row * PP + cb * 8;
    const bf16x8 hv = *(const bf16x8*)(Phi + o);
    const bf16x8 lv = *(const bf16x8*)(Plo + o);
    f32x4 o0, o1;
#pragma unroll
    for (int j = 0; j < 4; ++j) {
      o0[j] = (float)hv[j] + (float)lv[j];
      o1[j] = (float)hv[j + 4] + (float)lv[j + 4];
    }
    float* d = dst + row * 512 + cb * 8;
    *(f32x4*)d = o0;
    *(f32x4*)(d + 4) = o1;
  }
}

// One step on M=32 planes (1024 thr, 16 waves, wave owns 2 nt).
// <2,3>: a1b0,a1b1,a2b0.  <1,2>: a1b0,a2b0.
template <int NTERM, int NPROD, bool HAS_H>
__device__ __forceinline__ void pstep32(__bf16* Phi, __bf16* Plo,
                                        const __bf16* __restrict__ bfrag,
                                        const float* __restrict__ addbase,
                                        long addpitch) {
  const int tid = threadIdx.x, l = tid & 63, w = tid >> 6, g = l >> 4, li = l & 15;
  f32x4 addv[2][2];
#pragma unroll
  for (int mt = 0; mt < 2; ++mt)
#pragma unroll
    for (int q = 0; q < 2; ++q) {
      const int col = (w * 2 + q) * 16 + li;
#pragma unroll
      for (int r = 0; r < 4; ++r) {
        const int bat = mt * 16 + g * 4 + r;
        addv[mt][q][r] = addbase[(long)bat * addpitch + col];
      }
    }

  f32x4 acc[2][2] = {};
  if (HAS_H) {
#pragma unroll 4
    for (int kk = 0; kk < 16; ++kk) {
      bf16x8 b[NTERM][2];
#pragma unroll
      for (int q = 0; q < 2; ++q) {
        const long fo = (((long)(w * 2 + q) * 16 + kk) * 64 + l) * 8;
#pragma unroll
        for (int tt = 0; tt < NTERM; ++tt)
          b[tt][q] = *(const bf16x8*)(bfrag + (long)tt * TS + fo);
      }
#pragma unroll
      for (int mt = 0; mt < 2; ++mt) {
        const int o = (mt * 16 + li) * PP + kk * 32 + g * 8;
        const bf16x8 a1 = *(const bf16x8*)(Phi + o);
        const bf16x8 a2 = *(const bf16x8*)(Plo + o);
#pragma unroll
        for (int q = 0; q < 2; ++q) {
          acc[mt][q] = mfma16(a1, b[0][q], acc[mt][q]);
          if (NTERM >= 2) acc[mt][q] = mfma16(a1, b[1][q], acc[mt][q]);
          if (NPROD > NTERM) acc[mt][q] = mfma16(a2, b[0][q], acc[mt][q]);
          if (NPROD >= 4) acc[mt][q] = mfma16(a1, b[NTERM - 1][q], acc[mt][q]);
        }
      }
    }
    __syncthreads();  // plane reads done before overwrite
  }

#pragma unroll
  for (int mt = 0; mt < 2; ++mt)
#pragma unroll
    for (int q = 0; q < 2; ++q) {
      const int col = (w * 2 + q) * 16 + li;
#pragma unroll
      for (int r = 0; r < 4; ++r) {
        const float v = (HAS_H ? acc[mt][q][r] : 0.0f) + addv[mt][q][r];
        const int row = mt * 16 + g * 4 + r;
        const __bf16 hi = (__bf16)v;
        const int o = row * PP + col;
        Phi[o] = hi;
        Plo[o] = (__bf16)(v - (float)hi);
      }
    }
  __syncthreads();
}

// Double step: h <- h@R^2 + xw[t1]@R + xw[t2]; R lo-term dropped on xw path.
__device__ __forceinline__ void dstep(__bf16* Phi, __bf16* Plo,
                                      __bf16* Qhi, __bf16* Qlo,
                                      const __bf16* __restrict__ r2f,
                                      const __bf16* __restrict__ rf,
                                      const float* __restrict__ xw,
                                      long t1, long t2) {
  stage32p(xw + t1 * UDIM, TDIM * UDIM, Qhi, Qlo);
  __syncthreads();
  const int tid = threadIdx.x, l = tid & 63, w = tid >> 6, g = l >> 4, li = l & 15;
  f32x4 addv[2][2];
#pragma unroll
  for (int mt = 0; mt < 2; ++mt)
#pragma unroll
    for (int q = 0; q < 2; ++q) {
      const int col = (w * 2 + q) * 16 + li;
#pragma unroll
      for (int r = 0; r < 4; ++r) {
        const int bat = mt * 16 + g * 4 + r;
        addv[mt][q][r] = xw[(long)bat * (TDIM * UDIM) + t2 * UDIM + col];
      }
    }
  f32x4 acc[2][2] = {};
#pragma unroll 2
  for (int kk = 0; kk < 16; ++kk) {
    bf16x8 c0[2], c1[2], d0[2];
#pragma unroll
    for (int q = 0; q < 2; ++q) {
      const long fo = (((long)(w * 2 + q) * 16 + kk) * 64 + l) * 8;
      c0[q] = *(const bf16x8*)(r2f + fo);
      c1[q] = *(const bf16x8*)(r2f + TS + fo);
      d0[q] = *(const bf16x8*)(rf + fo);
    }
#pragma unroll
    for (int mt = 0; mt < 2; ++mt) {
      const int o = (mt * 16 + li) * PP + kk * 32 + g * 8;
      const bf16x8 h1 = *(const bf16x8*)(Phi + o);
      const bf16x8 h2 = *(const bf16x8*)(Plo + o);
      const bf16x8 q1 = *(const bf16x8*)(Qhi + o);
      const bf16x8 q2 = *(const bf16x8*)(Qlo + o);
#pragma unroll
      for (int q = 0; q < 2; ++q) {
        acc[mt][q] = mfma16(h1, c0[q], acc[mt][q]);
        acc[mt][q] = mfma16(q1, d0[q], acc[mt][q]);
        acc[mt][q] = mfma16(h1, c1[q], acc[mt][q]);
        acc[mt][q] = mfma16(h2, c0[q], acc[mt][q]);
        acc[mt][q] = mfma16(q2, d0[q], acc[mt][q]);
      }
    }
  }
  __syncthreads();
#pragma unroll
  for (int mt = 0; mt < 2; ++mt)
#pragma unroll
    for (int q = 0; q < 2; ++q) {
      const int col = (w * 2 + q) * 16 + li;
#pragma unroll
      for (int r = 0; r < 4; ++r) {
        const float v = acc[mt][q][r] + addv[mt][q][r];
        const int row = mt * 16 + g * 4 + r;
        const __bf16 hi = (__bf16)v;
        const int o = row * PP + col;
        Phi[o] = hi;
        Plo[o] = (__bf16)(v - (float)hi);
      }
    }
  __syncthreads();
}

// ---- device tasks ----------------------------------------------------------

// xW task, M=64: 512 thr = 8 waves; wave owns 4 nt; mt=0..3. W 1-term.
__device__ __forceinline__ void xw_dev(long blk, const float* __restrict__ x,
                                       const __bf16* __restrict__ wf,
                                       float* __restrict__ out, char* smem) {
  __bf16* Phi = (__bf16*)smem;  // [64][PP] hi-only = 66560 B
  const float* src = x + blk * ST64;
  for (int i = threadIdx.x; i < 4096; i += 512) {
    const int row = i >> 6, cb = i & 63;
    const f32x4 v0 = *(const f32x4*)(src + (long)row * 512 + cb * 8);
    const f32x4 v1 = *(const f32x4*)(src + (long)row * 512 + cb * 8 + 4);
    bf16x8 hv;
#pragma unroll
    for (int j = 0; j < 4; ++j) {
      hv[j] = (__bf16)v0[j];
      hv[j + 4] = (__bf16)v1[j];
    }
    *(bf16x8*)(Phi + row * PP + cb * 8) = hv;
  }
  __syncthreads();
  const int tid = threadIdx.x, l = tid & 63, w = tid >> 6, g = l >> 4, li = l & 15;
  f32x4 acc[4][4] = {};
#pragma unroll 4
  for (int kk = 0; kk < 16; ++kk) {
    bf16x8 b0[4];
#pragma unroll
    for (int q = 0; q < 4; ++q) {
      const long fo = (((long)(w * 4 + q) * 16 + kk) * 64 + l) * 8;
      b0[q] = *(const bf16x8*)(wf + fo);
    }
#pragma unroll
    for (int mt = 0; mt < 4; ++mt) {
      const bf16x8 a1 = *(const bf16x8*)(Phi + (mt * 16 + li) * PP + kk * 32 + g * 8);
#pragma unroll
      for (int q = 0; q < 4; ++q)
        acc[mt][q] = mfma16(a1, b0[q], acc[mt][q]);
    }
  }
  float* gdst = out + blk * ST64;
#pragma unroll
  for (int mt = 0; mt < 4; ++mt)
#pragma unroll
    for (int q = 0; q < 4; ++q) {
      const int col = (w * 4 + q) * 16 + li;
#pragma unroll
      for (int r = 0; r < 4; ++r)
        gdst[(long)(mt * 16 + g * 4 + r) * 512 + col] = acc[mt][q][r];
    }
}

// Stage a [32,512] fp32 state into swizzled LDS (512 thr).
__device__ __forceinline__ void stage_sw(const float* __restrict__ src,
                                         float* hbuf) {
  for (int i = threadIdx.x; i < 4096; i += 512) {
    const int flat = i * 4, row = flat >> 9, col = flat & 511;
    *(f32x4*)&hbuf[hidx(row, col)] = *(const f32x4*)&src[flat];
  }
}

// A @ Bfrag with A in swizzled LDS (2-term, 3 products).
__device__ __forceinline__ f32x4 lds_mm(const float* hbuf,
                                        const __bf16* __restrict__ bf,
                                        int mt, int ntg) {
  const int tid = threadIdx.x, l = tid & 63, g = (l >> 4) & 3, li = l & 15;
  f32x4 acc = {};
#pragma unroll 2
  for (int kk = 0; kk < 16; ++kk) {
    const long fo = (((long)ntg * 16 + kk) * 64 + l) * 8;
    const bf16x8 b0 = *(const bf16x8*)(bf + fo);
    const bf16x8 b1 = *(const bf16x8*)(bf + TS + fo);
    bf16x8 a1, a2;
    const float* pp = &hbuf[hidx(mt * 16 + li, kk * 32 + g * 8)];
#pragma unroll
    for (int j = 0; j < 8; ++j) {
      const float v = pp[j];
      const __bf16 hi = (__bf16)v;
      a1[j] = hi;
      a2[j] = (__bf16)(v - (float)hi);
    }
    acc = mfma16(a1, b0, acc);
    acc = mfma16(a1, b1, acc);
    acc = mfma16(a2, b0, acc);
  }
  return acc;
}

// Multiply task (128 blocks x 512 thr): out = A @ Bfrag, fp32 + frag split.
__device__ __forceinline__ void sq_dev(int b, const float* __restrict__ a,
                                       const __bf16* __restrict__ bf,
                                       float* __restrict__ of32,
                                       __bf16* __restrict__ ofr, float* hbuf) {
  const int rg = b >> 3, cg = b & 7;
  const int tid = threadIdx.x, l = tid & 63, w = tid >> 6, g = l >> 4, li = l & 15;
  stage_sw(a + (long)rg * ST32, hbuf);
  __syncthreads();
  const int mt = w >> 2, q = w & 3, ntg = cg * 4 + q;
  f32x4 acc = {};
#pragma unroll 2
  for (int kk = 0; kk < 16; ++kk) {
    const long fo = (((long)ntg * 16 + kk) * 64 + l) * 8;
    const bf16x8 b0 = *(const bf16x8*)(bf + fo);
    const bf16x8 b1 = *(const bf16x8*)(bf + TS + fo);
    const bf16x8 b2 = *(const bf16x8*)(bf + 2 * TS + fo);
    bf16x8 a1, a2;
    const float* pp = &hbuf[hidx(mt * 16 + li, kk * 32 + g * 8)];
#pragma unroll
    for (int j = 0; j < 8; ++j) {
      const float v = pp[j];
      const __bf16 hi = (__bf16)v;
      a1[j] = hi;
      a2[j] = (__bf16)(v - (float)hi);
    }
    acc = mfma16(a1, b0, acc);
    acc = mfma16(a1, b1, acc);
    acc = mfma16(a2, b0, acc);
    acc = mfma16(a1, b2, acc);
  }
  const int n = ntg * 16 + li;
#pragma unroll
  for (int r = 0; r < 4; ++r) {
    const int k = rg * 32 + mt * 16 + g * 4 + r;
    const float v = acc[r];
    of32[(long)k * 512 + n] = v;
    const __bf16 t1 = (__bf16)v;
    const float r1 = v - (float)t1;
    const __bf16 t2 = (__bf16)r1;
    const long fi = (((long)(n >> 4) * 16 + (k >> 5)) * 64 + ((k >> 3) & 3) * 16 + (n & 15)) * 8 + (k & 7);
    ofr[fi] = t1;
    ofr[TS + fi] = t2;
    ofr[2 * TS + fi] = (__bf16)(r1 - (float)t2);
  }
}

// Tree up-stage task (LDS-staged A): out[p] = in[2p] @ M + in[2p+1].
__device__ __forceinline__ void pair_dev(int b, const float* __restrict__ in,
                                         const __bf16* __restrict__ bf,
                                         float* __restrict__ outb, float* hbuf) {
  const int p = b >> 3, cs = b & 7;
  const int tid = threadIdx.x, l = tid & 63, w = tid >> 6, g = l >> 4, li = l & 15;
  stage_sw(in + (long)(2 * p) * ST32, hbuf);
  __syncthreads();
  const int mt = w >> 2, ntg = cs * 4 + (w & 3);
  const f32x4 acc = lds_mm(hbuf, bf, mt, ntg);
  const float* addp = in + (long)(2 * p + 1) * ST32;
  float* outp = outb + (long)p * ST32;
  const int col = ntg * 16 + li;
#pragma unroll
  for (int r = 0; r < 4; ++r) {
    const int row = mt * 16 + g * 4 + r;
    outp[(long)row * 512 + col] = acc[r] + addp[(long)row * 512 + col];
  }
}

// ---- kernels --------------------------------------------------------------

// Split two fp32 512x512 matrices into 3 bf16 terms (MFMA B-fragment order).
__global__ __launch_bounds__(512) void k_split2(const float* __restrict__ m0,
                                                const float* __restrict__ m1,
                                                __bf16* __restrict__ f0,
                                                __bf16* __restrict__ f1) {
  const int bb = blockIdx.x;
  const float* m = (bb < 512) ? m0 : m1;
  __bf16* f = (bb < 512) ? f0 : f1;
  const int idx = (bb & 511) * 512 + threadIdx.x;
  const int j = idx & 7, l = (idx >> 3) & 63, kk = (idx >> 9) & 15, nt = idx >> 13;
  const int k = kk * 32 + (l >> 4) * 8 + j;
  const int n = nt * 16 + (l & 15);
  const float v = m[k * 512 + n];
  const __bf16 t1 = (__bf16)v;
  const float r1 = v - (float)t1;
  const __bf16 t2 = (__bf16)r1;
  f[idx] = t1;
  f[TS + idx] = t2;
  f[2 * TS + idx] = (__bf16)(r1 - (float)t2);
}

// xW remainder kernel (base = first M=64 tile index).
__global__ __launch_bounds__(512) void k_xw(const float* __restrict__ x,
                                            const __bf16* __restrict__ wf,
                                            float* __restrict__ out, int base) {
  __shared__ __align__(16) char smem[64 * PP * 2];
  xw_dev(base + blockIdx.x, x, wf, out, smem);
}

// Co-dispatch: blocks 0-127 advance squaring chain; blocks 128+ do xw tiles.
__global__ __launch_bounds__(512) void k_xwsq(const float* __restrict__ sqa,
                                              const __bf16* __restrict__ sqbf,
                                              float* __restrict__ sqo32,
                                              __bf16* __restrict__ sqofr,
                                              const float* __restrict__ x,
                                              const __bf16* __restrict__ wf,
                                              float* __restrict__ out, int base) {
  __shared__ __align__(16) char smem[64 * PP * 2];
  const int b = blockIdx.x;
  if (b < 128)
    sq_dev(b, sqa, sqbf, sqo32, sqofr, (float*)smem);
  else
    xw_dev(base + (b - 128), x, wf, out, smem);
}

// Co-dispatch: blocks 0-127 squaring; blocks 128+ tree up-stage.
__global__ __launch_bounds__(512) void k_combo(const float* __restrict__ sqa,
                                               const __bf16* __restrict__ sqbf,
                                               float* __restrict__ sqo32,
                                               __bf16* __restrict__ sqofr,
                                               const float* __restrict__ prin,
                                               const __bf16* __restrict__ prbf,
                                               float* __restrict__ prout) {
  __shared__ float hbuf[ST32];
  const int b = blockIdx.x;
  if (b < 128)
    sq_dev(b, sqa, sqbf, sqo32, sqofr, hbuf);
  else
    pair_dev(b - 128, prin, prbf, prout, hbuf);
}

// Level-0 up-sweep: h = xw[t0]; 1 single step; 3 double steps. 2-term R.
__global__ __launch_bounds__(1024) void k_local(const float* __restrict__ xw,
                                                const __bf16* __restrict__ rf,
                                                const __bf16* __restrict__ r2f,
                                                float* __restrict__ sout) {
  __shared__ __bf16 Phi[32 * PP], Plo[32 * PP], Qhi[32 * PP], Qlo[32 * PP];
  const long c = blockIdx.x;
  stage32p(xw + c * 8 * UDIM, TDIM * UDIM, Phi, Plo);  // h = xw[t0]
  __syncthreads();
  pstep32<2, 3, true>(Phi, Plo, rf, xw + (c * 8 + 1) * UDIM, TDIM * UDIM);
  dstep(Phi, Plo, Qhi, Qlo, r2f, rf, xw, c * 8 + 2, c * 8 + 3);
  dstep(Phi, Plo, Qhi, Qlo, r2f, rf, xw, c * 8 + 4, c * 8 + 5);
  dstep(Phi, Plo, Qhi, Qlo, r2f, rf, xw, c * 8 + 6, c * 8 + 7);
  write_flat(Phi, Plo, sout + c * ST32);
}

// Final pass with fused down-k=1 and register-cached R frags (kk<6).
//   even chunk c=2p:  entry = E1[p]
//   odd  chunk c=2p+1: entry = E1[p]@R^8 + S[2p]   (2-term R^8)
// 8 serial 1-term-R steps; h written via planes + write_bt (coalesced).
__global__ __launch_bounds__(1024) void k_fix0(const float* __restrict__ e1,
                                               const float* __restrict__ sbuf,
                                               float* out,
                                               const __bf16* __restrict__ rf,
                                               const __bf16* __restrict__ r8f) {
  __shared__ __bf16 Phi[32 * PP], Plo[32 * PP];
  const long c = blockIdx.x;
  stage32p(e1 + (c >> 1) * ST32, 512, Phi, Plo);
  __syncthreads();
  if (c & 1)
    pstep32<2, 3, true>(Phi, Plo, r8f, sbuf + (c - 1) * ST32, 512);

  const int tid = threadIdx.x, l = tid & 63, w = tid >> 6, g = l >> 4, li = l & 15;
  // Register-cache the first 6 kk-slices of the 1-term R frag (identical
  // across all 8 steps).
  bf16x8 bc[6][2];
#pragma unroll
  for (int kk = 0; kk < 6; ++kk)
#pragma unroll
    for (int q = 0; q < 2; ++q)
      bc[kk][q] = *(const bf16x8*)(rf + (((long)(w * 2 + q) * 16 + kk) * 64 + l) * 8);

  for (int j = 0; j < 8; ++j) {
    const float* addbase = out + (c * 8 + j) * UDIM;
    f32x4 addv[2][2];
#pragma unroll
    for (int mt = 0; mt < 2; ++mt)
#pragma unroll
      for (int q = 0; q < 2; ++q) {
        const int col = (w * 2 + q) * 16 + li;
#pragma unroll
        for (int r = 0; r < 4; ++r) {
          const int bat = mt * 16 + g * 4 + r;
          addv[mt][q][r] = addbase[(long)bat * (TDIM * UDIM) + col];
        }
      }
    f32x4 acc[2][2] = {};
#pragma unroll
    for (int kk = 0; kk < 16; ++kk) {
      bf16x8 b0[2];
      if (kk < 6) {
        b0[0] = bc[kk][0];
        b0[1] = bc[kk][1];
      } else {
#pragma unroll
        for (int q = 0; q < 2; ++q)
          b0[q] = *(const bf16x8*)(rf + (((long)(w * 2 + q) * 16 + kk) * 64 + l) * 8);
      }
#pragma unroll
      for (int mt = 0; mt < 2; ++mt) {
        const int o = (mt * 16 + li) * PP + kk * 32 + g * 8;
        const bf16x8 a1 = *(const bf16x8*)(Phi + o);
        const bf16x8 a2 = *(const bf16x8*)(Plo + o);
#pragma unroll
        for (int q = 0; q < 2; ++q) {
          acc[mt][q] = mfma16(a1, b0[q], acc[mt][q]);
          acc[mt][q] = mfma16(a2, b0[q], acc[mt][q]);
        }
      }
    }
    __syncthreads();  // plane reads done before overwrite
#pragma unroll
    for (int mt = 0; mt < 2; ++mt)
#pragma unroll
      for (int q = 0; q < 2; ++q) {
        const int col = (w * 2 + q) * 16 + li;
#pragma unroll
        for (int r = 0; r < 4; ++r) {
          const float v = acc[mt][q][r] + addv[mt][q][r];
          const int row = mt * 16 + g * 4 + r;
          const __bf16 hi = (__bf16)v;
          const int o = row * PP + col;
          Phi[o] = hi;
          Plo[o] = (__bf16)(v - (float)hi);
        }
      }
    __syncthreads();
    write_bt(Phi, Plo, out, c * 8 + j);   // full-row coalesced h write
    __syncthreads();
  }
}

// Tree down-stage (LDS-staged parent), in place into child-level buffer:
//   ulev[2p+1] = epar[p] @ M + ulev[2p];  ulev[2p] = epar[p]
__global__ __launch_bounds__(512) void k_down(const float* __restrict__ epar,
                                              float* __restrict__ ulev,
                                              const __bf16* __restrict__ bf) {
  __shared__ float hbuf[ST32];
  const int p = blockIdx.x >> 3, cs = blockIdx.x & 7;
  const int tid = threadIdx.x, l = tid & 63, w = tid >> 6, g = l >> 4, li = l & 15;
  stage_sw(epar + (long)p * ST32, hbuf);
  __syncthreads();
  const int mt = w >> 2, ntg = cs * 4 + (w & 3);
  const f32x4 acc = lds_mm(hbuf, bf, mt, ntg);
  float* evp = ulev + (long)(2 * p) * ST32;
  float* outp = ulev + (long)(2 * p + 1) * ST32;
  const int col = ntg * 16 + li;
  float cp[4];
#pragma unroll
  for (int r = 0; r < 4; ++r) {
    const int row = mt * 16 + g * 4 + r;
    const long off = (long)row * 512 + col;
    cp[r] = hbuf[hidx(row, col)];     // = epar[p][row][col], exact
    outp[off] = acc[r] + evp[off];
  }
  __syncthreads();
#pragma unroll
  for (int r = 0; r < 4; ++r) {
    const int row = mt * 16 + g * 4 + r;
    evp[(long)row * 512 + col] = cp[r];
  }
}

extern "C" void kernel_launch(void* const* d_in, const int* in_sizes, int n_in,
                              void* d_out, int out_size, void* d_ws, size_t ws_size,
                              hipStream_t stream) {
  (void)in_sizes; (void)n_in; (void)out_size; (void)ws_size;
  const float* x  = (const float*)d_in[0];
  const float* W  = (const float*)d_in[1];
  const float* R  = (const float*)d_in[2];
  const float* h0 = (const float*)d_in[3];
  float* out = (float*)d_out;

  __bf16* F  = (__bf16*)d_ws;          // F[i] = frags of R^(2^i), i=0..10
  __bf16* Fw = F + 11 * FE;            // frags of W
  float* P1 = (float*)(Fw + FE);
  float* P2 = P1 + TS;
  float* Sbuf = P2 + TS;               // 256 chunk sums (S) -- preserved
  float* Ub[8];
  {
    float* up = Sbuf + 256 * ST32;
    for (int k = 1; k <= 7; ++k) { Ub[k] = up; up += (1L << (8 - k)) * ST32; }
  }

  k_split2<<<1024, 512, 0, stream>>>(W, R, Fw, F);

  // Head squarings co-dispatched with xw slices (256 M=64 tiles each):
  //   F[1]=R^2 ; F[2]=R^4 ; F[3]=R^8  (fp32 ping-pong, frag split fused)
  k_xwsq<<<384, 512, 0, stream>>>(R, F, P1, F + FE, x, Fw, out, 0);
  k_xwsq<<<384, 512, 0, stream>>>(P1, F + FE, P2, F + 2L * FE, x, Fw, out, 256);
  k_xwsq<<<384, 512, 0, stream>>>(P2, F + 2L * FE, P1, F + 3L * FE, x, Fw, out, 512);
  k_xw<<<256, 512, 0, stream>>>(x, Fw, out, 768);

  k_local<<<256, 1024, 0, stream>>>(out, F, F + FE, Sbuf);

  // phases k=1..7: sq (F[k+3] <- F[k+2], fp32 ping-pong) || tree-up stage k
  for (int k = 1; k <= 7; ++k) {
    const int i = k + 3;  // chain index being produced
    const float* sqa = (i & 1) ? P2 : P1;   // fp32 of R^(2^(i-1))
    float* sqo = (i & 1) ? P1 : P2;
    const float* prin = (k == 1) ? Sbuf : Ub[k - 1];
    const int npr = (1 << (8 - k)) * 8;
    k_combo<<<128 + npr, 512, 0, stream>>>(sqa, F + (long)(i - 1) * FE, sqo,
                                           F + (long)i * FE, prin,
                                           F + (long)(k + 2) * FE, Ub[k]);
  }

  // down-sweep k=7..2 (k=1 fused into fix0); E1 lands in Ub[1], S stays in Sbuf
  k_down<<<8, 512, 0, stream>>>(h0, Ub[7], F + 10L * FE);
  for (int k = 7; k >= 2; --k)
    k_down<<<(1 << (8 - k)) * 8, 512, 0, stream>>>(Ub[k], Ub[k - 1], F + (long)(k + 2) * FE);

  k_fix0<<<256, 1024, 0, stream>>>(Ub[1], Sbuf, out, F, F + 3L * FE);
}

// Round 18
// 444.668 us; speedup vs baseline: 1.1267x; 1.1267x over previous
//
#include <hip/hip_runtime.h>
#include <hip/hip_bf16.h>

// Linear recurrence h_t = x_t@W + h_{t-1}@R, parallel scan, chunk C=8.
// R18 = R15 (461us, best) + k_local dstep d1-drop (verified safe R16/R17).
// R16/R17's fix0 register cache REMOVED: at 1024-thr blocks hipcc caps
// VGPR at 64; the 48-VGPR cache spilled to scratch (FETCH 94->319 MB,
// WRITE +59 MB = scratch traffic). Lesson: check VGPR_Count vs live state.

typedef float f32x4 __attribute__((ext_vector_type(4)));
typedef __bf16 bf16x8 __attribute__((ext_vector_type(8)));

#define TDIM 2048L
#define UDIM 512L
#define ST32 16384L     // elems per [32,512] state
#define ST64 32768L     // elems per [64,512] tile
#define TS 262144L      // elems per frag term
#define FE 786432L      // elems per 3-term frag matrix
#define PP 520          // padded plane row stride (bf16 elems)

__device__ __forceinline__ f32x4 mfma16(bf16x8 a, bf16x8 b, f32x4 c) {
  return __builtin_amdgcn_mfma_f32_16x16x32_bf16(a, b, c, 0, 0, 0);
}

// fp32 [32][512] swizzle (staging for sq/pair/down)
__device__ __forceinline__ int hidx(int row, int col) {
  return row * 512 + (col ^ ((row & 7) << 3));
}

__device__ __forceinline__ void pack8(const f32x4& v0, const f32x4& v1,
                                      bf16x8& hv, bf16x8& lv) {
#pragma unroll
  for (int j = 0; j < 4; ++j) {
    const float a = v0[j];
    const __bf16 ha = (__bf16)a;
    hv[j] = ha; lv[j] = (__bf16)(a - (float)ha);
    const float b = v1[j];
    const __bf16 hb = (__bf16)b;
    hv[j + 4] = hb; lv[j + 4] = (__bf16)(b - (float)hb);
  }
}

// ---- M=32 pair-plane helpers (stride PP, blockDim-stride loops) -----------

__device__ __forceinline__ void stage32p(const float* __restrict__ src,
                                         long pitch, __bf16* Phi, __bf16* Plo) {
  for (int i = threadIdx.x; i < 2048; i += blockDim.x) {
    const int row = i >> 6, cb = i & 63;
    const float* p = src + (long)row * pitch + cb * 8;
    bf16x8 hv, lv;
    pack8(*(const f32x4*)p, *(const f32x4*)(p + 4), hv, lv);
    const int o = row * PP + cb * 8;
    *(bf16x8*)(Phi + o) = hv;
    *(bf16x8*)(Plo + o) = lv;
  }
}

// planes -> out[B,T,U] at time t (fp32 = hi+lo), full-row coalesced stores
__device__ __forceinline__ void write_bt(const __bf16* Phi, const __bf16* Plo,
                                         float* out, long t) {
  for (int i = threadIdx.x; i < 2048; i += blockDim.x) {
    const int row = i >> 6, cb = i & 63;
    const int o = row * PP + cb * 8;
    const bf16x8 hv = *(const bf16x8*)(Phi + o);
    const bf16x8 lv = *(const bf16x8*)(Plo + o);
    f32x4 o0, o1;
#pragma unroll
    for (int j = 0; j < 4; ++j) {
      o0[j] = (float)hv[j] + (float)lv[j];
      o1[j] = (float)hv[j + 4] + (float)lv[j + 4];
    }
    float* dst = out + (long)row * (TDIM * UDIM) + t * UDIM + cb * 8;
    *(f32x4*)dst = o0;
    *(f32x4*)(dst + 4) = o1;
  }
}

__device__ __forceinline__ void write_flat(const __bf16* Phi, const __bf16* Plo,
                                           float* dst) {
  for (int i = threadIdx.x; i < 2048; i += blockDim.x) {
    const int row = i >> 6, cb = i & 63;
    const int o = row * PP + cb * 8;
    const bf16x8 hv = *(const bf16x8*)(Phi + o);
    const bf16x8 lv = *(const bf16x8*)(Plo + o);
    f32x4 o0, o1;
#pragma unroll
    for (int j = 0; j < 4; ++j) {
      o0[j] = (float)hv[j] + (float)lv[j];
      o1[j] = (float)hv[j + 4] + (float)lv[j + 4];
    }
    float* d = dst + row * 512 + cb * 8;
    *(f32x4*)d = o0;
    *(f32x4*)(d + 4) = o1;
  }
}

// One step on M=32 planes (1024 thr, 16 waves, wave owns 2 nt).
// <2,3>: a1b0,a1b1,a2b0.  <1,2>: a1b0,a2b0.
template <int NTERM, int NPROD, bool HAS_H>
__device__ __forceinline__ void pstep32(__bf16* Phi, __bf16* Plo,
                                        const __bf16* __restrict__ bfrag,
                                        const float* __restrict__ addbase,
                                        long addpitch) {
  const int tid = threadIdx.x, l = tid & 63, w = tid >> 6, g = l >> 4, li = l & 15;
  f32x4 addv[2][2];
#pragma unroll
  for (int mt = 0; mt < 2; ++mt)
#pragma unroll
    for (int q = 0; q < 2; ++q) {
      const int col = (w * 2 + q) * 16 + li;
#pragma unroll
      for (int r = 0; r < 4; ++r) {
        const int bat = mt * 16 + g * 4 + r;
        addv[mt][q][r] = addbase[(long)bat * addpitch + col];
      }
    }

  f32x4 acc[2][2] = {};
  if (HAS_H) {
#pragma unroll 4
    for (int kk = 0; kk < 16; ++kk) {
      bf16x8 b[NTERM][2];
#pragma unroll
      for (int q = 0; q < 2; ++q) {
        const long fo = (((long)(w * 2 + q) * 16 + kk) * 64 + l) * 8;
#pragma unroll
        for (int tt = 0; tt < NTERM; ++tt)
          b[tt][q] = *(const bf16x8*)(bfrag + (long)tt * TS + fo);
      }
#pragma unroll
      for (int mt = 0; mt < 2; ++mt) {
        const int o = (mt * 16 + li) * PP + kk * 32 + g * 8;
        const bf16x8 a1 = *(const bf16x8*)(Phi + o);
        const bf16x8 a2 = *(const bf16x8*)(Plo + o);
#pragma unroll
        for (int q = 0; q < 2; ++q) {
          acc[mt][q] = mfma16(a1, b[0][q], acc[mt][q]);
          if (NTERM >= 2) acc[mt][q] = mfma16(a1, b[1][q], acc[mt][q]);
          if (NPROD > NTERM) acc[mt][q] = mfma16(a2, b[0][q], acc[mt][q]);
          if (NPROD >= 4) acc[mt][q] = mfma16(a1, b[NTERM - 1][q], acc[mt][q]);
        }
      }
    }
    __syncthreads();  // plane reads done before overwrite
  }

#pragma unroll
  for (int mt = 0; mt < 2; ++mt)
#pragma unroll
    for (int q = 0; q < 2; ++q) {
      const int col = (w * 2 + q) * 16 + li;
#pragma unroll
      for (int r = 0; r < 4; ++r) {
        const float v = (HAS_H ? acc[mt][q][r] : 0.0f) + addv[mt][q][r];
        const int row = mt * 16 + g * 4 + r;
        const __bf16 hi = (__bf16)v;
        const int o = row * PP + col;
        Phi[o] = hi;
        Plo[o] = (__bf16)(v - (float)hi);
      }
    }
  __syncthreads();
}

// Double step: h <- h@R^2 + xw[t1]@R + xw[t2]; R lo-term dropped on xw path.
__device__ __forceinline__ void dstep(__bf16* Phi, __bf16* Plo,
                                      __bf16* Qhi, __bf16* Qlo,
                                      const __bf16* __restrict__ r2f,
                                      const __bf16* __restrict__ rf,
                                      const float* __restrict__ xw,
                                      long t1, long t2) {
  stage32p(xw + t1 * UDIM, TDIM * UDIM, Qhi, Qlo);
  __syncthreads();
  const int tid = threadIdx.x, l = tid & 63, w = tid >> 6, g = l >> 4, li = l & 15;
  f32x4 addv[2][2];
#pragma unroll
  for (int mt = 0; mt < 2; ++mt)
#pragma unroll
    for (int q = 0; q < 2; ++q) {
      const int col = (w * 2 + q) * 16 + li;
#pragma unroll
      for (int r = 0; r < 4; ++r) {
        const int bat = mt * 16 + g * 4 + r;
        addv[mt][q][r] = xw[(long)bat * (TDIM * UDIM) + t2 * UDIM + col];
      }
    }
  f32x4 acc[2][2] = {};
#pragma unroll 2
  for (int kk = 0; kk < 16; ++kk) {
    bf16x8 c0[2], c1[2], d0[2];
#pragma unroll
    for (int q = 0; q < 2; ++q) {
      const long fo = (((long)(w * 2 + q) * 16 + kk) * 64 + l) * 8;
      c0[q] = *(const bf16x8*)(r2f + fo);
      c1[q] = *(const bf16x8*)(r2f + TS + fo);
      d0[q] = *(const bf16x8*)(rf + fo);
    }
#pragma unroll
    for (int mt = 0; mt < 2; ++mt) {
      const int o = (mt * 16 + li) * PP + kk * 32 + g * 8;
      const bf16x8 h1 = *(const bf16x8*)(Phi + o);
      const bf16x8 h2 = *(const bf16x8*)(Plo + o);
      const bf16x8 q1 = *(const bf16x8*)(Qhi + o);
      const bf16x8 q2 = *(const bf16x8*)(Qlo + o);
#pragma unroll
      for (int q = 0; q < 2; ++q) {
        acc[mt][q] = mfma16(h1, c0[q], acc[mt][q]);
        acc[mt][q] = mfma16(q1, d0[q], acc[mt][q]);
        acc[mt][q] = mfma16(h1, c1[q], acc[mt][q]);
        acc[mt][q] = mfma16(h2, c0[q], acc[mt][q]);
        acc[mt][q] = mfma16(q2, d0[q], acc[mt][q]);
      }
    }
  }
  __syncthreads();
#pragma unroll
  for (int mt = 0; mt < 2; ++mt)
#pragma unroll
    for (int q = 0; q < 2; ++q) {
      const int col = (w * 2 + q) * 16 + li;
#pragma unroll
      for (int r = 0; r < 4; ++r) {
        const float v = acc[mt][q][r] + addv[mt][q][r];
        const int row = mt * 16 + g * 4 + r;
        const __bf16 hi = (__bf16)v;
        const int o = row * PP + col;
        Phi[o] = hi;
        Plo[o] = (__bf16)(v - (float)hi);
      }
    }
  __syncthreads();
}

// ---- device tasks ----------------------------------------------------------

// xW task, M=64: 512 thr = 8 waves; wave owns 4 nt; mt=0..3. W 1-term.
__device__ __forceinline__ void xw_dev(long blk, const float* __restrict__ x,
                                       const __bf16* __restrict__ wf,
                                       float* __restrict__ out, char* smem) {
  __bf16* Phi = (__bf16*)smem;  // [64][PP] hi-only = 66560 B
  const float* src = x + blk * ST64;
  for (int i = threadIdx.x; i < 4096; i += 512) {
    const int row = i >> 6, cb = i & 63;
    const f32x4 v0 = *(const f32x4*)(src + (long)row * 512 + cb * 8);
    const f32x4 v1 = *(const f32x4*)(src + (long)row * 512 + cb * 8 + 4);
    bf16x8 hv;
#pragma unroll
    for (int j = 0; j < 4; ++j) {
      hv[j] = (__bf16)v0[j];
      hv[j + 4] = (__bf16)v1[j];
    }
    *(bf16x8*)(Phi + row * PP + cb * 8) = hv;
  }
  __syncthreads();
  const int tid = threadIdx.x, l = tid & 63, w = tid >> 6, g = l >> 4, li = l & 15;
  f32x4 acc[4][4] = {};
#pragma unroll 4
  for (int kk = 0; kk < 16; ++kk) {
    bf16x8 b0[4];
#pragma unroll
    for (int q = 0; q < 4; ++q) {
      const long fo = (((long)(w * 4 + q) * 16 + kk) * 64 + l) * 8;
      b0[q] = *(const bf16x8*)(wf + fo);
    }
#pragma unroll
    for (int mt = 0; mt < 4; ++mt) {
      const bf16x8 a1 = *(const bf16x8*)(Phi + (mt * 16 + li) * PP + kk * 32 + g * 8);
#pragma unroll
      for (int q = 0; q < 4; ++q)
        acc[mt][q] = mfma16(a1, b0[q], acc[mt][q]);
    }
  }
  float* gdst = out + blk * ST64;
#pragma unroll
  for (int mt = 0; mt < 4; ++mt)
#pragma unroll
    for (int q = 0; q < 4; ++q) {
      const int col = (w * 4 + q) * 16 + li;
#pragma unroll
      for (int r = 0; r < 4; ++r)
        gdst[(long)(mt * 16 + g * 4 + r) * 512 + col] = acc[mt][q][r];
    }
}

// Stage a [32,512] fp32 state into swizzled LDS (512 thr).
__device__ __forceinline__ void stage_sw(const float* __restrict__ src,
                                         float* hbuf) {
  for (int i = threadIdx.x; i < 4096; i += 512) {
    const int flat = i * 4, row = flat >> 9, col = flat & 511;
    *(f32x4*)&hbuf[hidx(row, col)] = *(const f32x4*)&src[flat];
  }
}

// A @ Bfrag with A in swizzled LDS (2-term, 3 products).
__device__ __forceinline__ f32x4 lds_mm(const float* hbuf,
                                        const __bf16* __restrict__ bf,
                                        int mt, int ntg) {
  const int tid = threadIdx.x, l = tid & 63, g = (l >> 4) & 3, li = l & 15;
  f32x4 acc = {};
#pragma unroll 2
  for (int kk = 0; kk < 16; ++kk) {
    const long fo = (((long)ntg * 16 + kk) * 64 + l) * 8;
    const bf16x8 b0 = *(const bf16x8*)(bf + fo);
    const bf16x8 b1 = *(const bf16x8*)(bf + TS + fo);
    bf16x8 a1, a2;
    const float* pp = &hbuf[hidx(mt * 16 + li, kk * 32 + g * 8)];
#pragma unroll
    for (int j = 0; j < 8; ++j) {
      const float v = pp[j];
      const __bf16 hi = (__bf16)v;
      a1[j] = hi;
      a2[j] = (__bf16)(v - (float)hi);
    }
    acc = mfma16(a1, b0, acc);
    acc = mfma16(a1, b1, acc);
    acc = mfma16(a2, b0, acc);
  }
  return acc;
}

// Multiply task (128 blocks x 512 thr): out = A @ Bfrag, fp32 + frag split.
__device__ __forceinline__ void sq_dev(int b, const float* __restrict__ a,
                                       const __bf16* __restrict__ bf,
                                       float* __restrict__ of32,
                                       __bf16* __restrict__ ofr, float* hbuf) {
  const int rg = b >> 3, cg = b & 7;
  const int tid = threadIdx.x, l = tid & 63, w = tid >> 6, g = l >> 4, li = l & 15;
  stage_sw(a + (long)rg * ST32, hbuf);
  __syncthreads();
  const int mt = w >> 2, q = w & 3, ntg = cg * 4 + q;
  f32x4 acc = {};
#pragma unroll 2
  for (int kk = 0; kk < 16; ++kk) {
    const long fo = (((long)ntg * 16 + kk) * 64 + l) * 8;
    const bf16x8 b0 = *(const bf16x8*)(bf + fo);
    const bf16x8 b1 = *(const bf16x8*)(bf + TS + fo);
    const bf16x8 b2 = *(const bf16x8*)(bf + 2 * TS + fo);
    bf16x8 a1, a2;
    const float* pp = &hbuf[hidx(mt * 16 + li, kk * 32 + g * 8)];
#pragma unroll
    for (int j = 0; j < 8; ++j) {
      const float v = pp[j];
      const __bf16 hi = (__bf16)v;
      a1[j] = hi;
      a2[j] = (__bf16)(v - (float)hi);
    }
    acc = mfma16(a1, b0, acc);
    acc = mfma16(a1, b1, acc);
    acc = mfma16(a2, b0, acc);
    acc = mfma16(a1, b2, acc);
  }
  const int n = ntg * 16 + li;
#pragma unroll
  for (int r = 0; r < 4; ++r) {
    const int k = rg * 32 + mt * 16 + g * 4 + r;
    const float v = acc[r];
    of32[(long)k * 512 + n] = v;
    const __bf16 t1 = (__bf16)v;
    const float r1 = v - (float)t1;
    const __bf16 t2 = (__bf16)r1;
    const long fi = (((long)(n >> 4) * 16 + (k >> 5)) * 64 + ((k >> 3) & 3) * 16 + (n & 15)) * 8 + (k & 7);
    ofr[fi] = t1;
    ofr[TS + fi] = t2;
    ofr[2 * TS + fi] = (__bf16)(r1 - (float)t2);
  }
}

// Tree up-stage task (LDS-staged A): out[p] = in[2p] @ M + in[2p+1].
__device__ __forceinline__ void pair_dev(int b, const float* __restrict__ in,
                                         const __bf16* __restrict__ bf,
                                         float* __restrict__ outb, float* hbuf) {
  const int p = b >> 3, cs = b & 7;
  const int tid = threadIdx.x, l = tid & 63, w = tid >> 6, g = l >> 4, li = l & 15;
  stage_sw(in + (long)(2 * p) * ST32, hbuf);
  __syncthreads();
  const int mt = w >> 2, ntg = cs * 4 + (w & 3);
  const f32x4 acc = lds_mm(hbuf, bf, mt, ntg);
  const float* addp = in + (long)(2 * p + 1) * ST32;
  float* outp = outb + (long)p * ST32;
  const int col = ntg * 16 + li;
#pragma unroll
  for (int r = 0; r < 4; ++r) {
    const int row = mt * 16 + g * 4 + r;
    outp[(long)row * 512 + col] = acc[r] + addp[(long)row * 512 + col];
  }
}

// ---- kernels --------------------------------------------------------------

// Split two fp32 512x512 matrices into 3 bf16 terms (MFMA B-fragment order).
__global__ __launch_bounds__(512) void k_split2(const float* __restrict__ m0,
                                                const float* __restrict__ m1,
                                                __bf16* __restrict__ f0,
                                                __bf16* __restrict__ f1) {
  const int bb = blockIdx.x;
  const float* m = (bb < 512) ? m0 : m1;
  __bf16* f = (bb < 512) ? f0 : f1;
  const int idx = (bb & 511) * 512 + threadIdx.x;
  const int j = idx & 7, l = (idx >> 3) & 63, kk = (idx >> 9) & 15, nt = idx >> 13;
  const int k = kk * 32 + (l >> 4) * 8 + j;
  const int n = nt * 16 + (l & 15);
  const float v = m[k * 512 + n];
  const __bf16 t1 = (__bf16)v;
  const float r1 = v - (float)t1;
  const __bf16 t2 = (__bf16)r1;
  f[idx] = t1;
  f[TS + idx] = t2;
  f[2 * TS + idx] = (__bf16)(r1 - (float)t2);
}

// xW remainder kernel (base = first M=64 tile index).
__global__ __launch_bounds__(512) void k_xw(const float* __restrict__ x,
                                            const __bf16* __restrict__ wf,
                                            float* __restrict__ out, int base) {
  __shared__ __align__(16) char smem[64 * PP * 2];
  xw_dev(base + blockIdx.x, x, wf, out, smem);
}

// Co-dispatch: blocks 0-127 advance squaring chain; blocks 128+ do xw tiles.
__global__ __launch_bounds__(512) void k_xwsq(const float* __restrict__ sqa,
                                              const __bf16* __restrict__ sqbf,
                                              float* __restrict__ sqo32,
                                              __bf16* __restrict__ sqofr,
                                              const float* __restrict__ x,
                                              const __bf16* __restrict__ wf,
                                              float* __restrict__ out, int base) {
  __shared__ __align__(16) char smem[64 * PP * 2];
  const int b = blockIdx.x;
  if (b < 128)
    sq_dev(b, sqa, sqbf, sqo32, sqofr, (float*)smem);
  else
    xw_dev(base + (b - 128), x, wf, out, smem);
}

// Co-dispatch: blocks 0-127 squaring; blocks 128+ tree up-stage.
__global__ __launch_bounds__(512) void k_combo(const float* __restrict__ sqa,
                                               const __bf16* __restrict__ sqbf,
                                               float* __restrict__ sqo32,
                                               __bf16* __restrict__ sqofr,
                                               const float* __restrict__ prin,
                                               const __bf16* __restrict__ prbf,
                                               float* __restrict__ prout) {
  __shared__ float hbuf[ST32];
  const int b = blockIdx.x;
  if (b < 128)
    sq_dev(b, sqa, sqbf, sqo32, sqofr, hbuf);
  else
    pair_dev(b - 128, prin, prbf, prout, hbuf);
}

// Level-0 up-sweep: h = xw[t0]; 1 single step; 3 double steps. 2-term R.
__global__ __launch_bounds__(1024) void k_local(const float* __restrict__ xw,
                                                const __bf16* __restrict__ rf,
                                                const __bf16* __restrict__ r2f,
                                                float* __restrict__ sout) {
  __shared__ __bf16 Phi[32 * PP], Plo[32 * PP], Qhi[32 * PP], Qlo[32 * PP];
  const long c = blockIdx.x;
  stage32p(xw + c * 8 * UDIM, TDIM * UDIM, Phi, Plo);  // h = xw[t0]
  __syncthreads();
  pstep32<2, 3, true>(Phi, Plo, rf, xw + (c * 8 + 1) * UDIM, TDIM * UDIM);
  dstep(Phi, Plo, Qhi, Qlo, r2f, rf, xw, c * 8 + 2, c * 8 + 3);
  dstep(Phi, Plo, Qhi, Qlo, r2f, rf, xw, c * 8 + 4, c * 8 + 5);
  dstep(Phi, Plo, Qhi, Qlo, r2f, rf, xw, c * 8 + 6, c * 8 + 7);
  write_flat(Phi, Plo, sout + c * ST32);
}

// Final pass with fused down-k=1 (R15 structure, no register cache):
//   even chunk c=2p:  entry = E1[p]
//   odd  chunk c=2p+1: entry = E1[p]@R^8 + S[2p]   (2-term R^8)
// 8 serial 1-term-R steps; h written via planes + write_bt (coalesced).
__global__ __launch_bounds__(1024) void k_fix0(const float* __restrict__ e1,
                                               const float* __restrict__ sbuf,
                                               float* out,
                                               const __bf16* __restrict__ rf,
                                               const __bf16* __restrict__ r8f) {
  __shared__ __bf16 Phi[32 * PP], Plo[32 * PP];
  const long c = blockIdx.x;
  stage32p(e1 + (c >> 1) * ST32, 512, Phi, Plo);
  __syncthreads();
  if (c & 1)
    pstep32<2, 3, true>(Phi, Plo, r8f, sbuf + (c - 1) * ST32, 512);
  for (int j = 0; j < 8; ++j) {
    pstep32<1, 2, true>(Phi, Plo, rf, out + (c * 8 + j) * UDIM, TDIM * UDIM);
    write_bt(Phi, Plo, out, c * 8 + j);
  }
}

// Tree down-stage (LDS-staged parent), in place into child-level buffer:
//   ulev[2p+1] = epar[p] @ M + ulev[2p];  ulev[2p] = epar[p]
__global__ __launch_bounds__(512) void k_down(const float* __restrict__ epar,
                                              float* __restrict__ ulev,
                                              const __bf16* __restrict__ bf) {
  __shared__ float hbuf[ST32];
  const int p = blockIdx.x >> 3, cs = blockIdx.x & 7;
  const int tid = threadIdx.x, l = tid & 63, w = tid >> 6, g = l >> 4, li = l & 15;
  stage_sw(epar + (long)p * ST32, hbuf);
  __syncthreads();
  const int mt = w >> 2, ntg = cs * 4 + (w & 3);
  const f32x4 acc = lds_mm(hbuf, bf, mt, ntg);
  float* evp = ulev + (long)(2 * p) * ST32;
  float* outp = ulev + (long)(2 * p + 1) * ST32;
  const int col = ntg * 16 + li;
  float cp[4];
#pragma unroll
  for (int r = 0; r < 4; ++r) {
    const int row = mt * 16 + g * 4 + r;
    const long off = (long)row * 512 + col;
    cp[r] = hbuf[hidx(row, col)];     // = epar[p][row][col], exact
    outp[off] = acc[r] + evp[off];
  }
  __syncthreads();
#pragma unroll
  for (int r = 0; r < 4; ++r) {
    const int row = mt * 16 + g * 4 + r;
    evp[(long)row * 512 + col] = cp[r];
  }
}

extern "C" void kernel_launch(void* const* d_in, const int* in_sizes, int n_in,
                              void* d_out, int out_size, void* d_ws, size_t ws_size,
                              hipStream_t stream) {
  (void)in_sizes; (void)n_in; (void)out_size; (void)ws_size;
  const float* x  = (const float*)d_in[0];
  const float* W  = (const float*)d_in[1];
  const float* R  = (const float*)d_in[2];
  const float* h0 = (const float*)d_in[3];
  float* out = (float*)d_out;

  __bf16* F  = (__bf16*)d_ws;          // F[i] = frags of R^(2^i), i=0..10
  __bf16* Fw = F + 11 * FE;            // frags of W
  float* P1 = (float*)(Fw + FE);
  float* P2 = P1 + TS;
  float* Sbuf = P2 + TS;               // 256 chunk sums (S) -- preserved
  float* Ub[8];
  {
    float* up = Sbuf + 256 * ST32;
    for (int k = 1; k <= 7; ++k) { Ub[k] = up; up += (1L << (8 - k)) * ST32; }
  }

  k_split2<<<1024, 512, 0, stream>>>(W, R, Fw, F);

  // Head squarings co-dispatched with xw slices (256 M=64 tiles each):
  //   F[1]=R^2 ; F[2]=R^4 ; F[3]=R^8  (fp32 ping-pong, frag split fused)
  k_xwsq<<<384, 512, 0, stream>>>(R, F, P1, F + FE, x, Fw, out, 0);
  k_xwsq<<<384, 512, 0, stream>>>(P1, F + FE, P2, F + 2L * FE, x, Fw, out, 256);
  k_xwsq<<<384, 512, 0, stream>>>(P2, F + 2L * FE, P1, F + 3L * FE, x, Fw, out, 512);
  k_xw<<<256, 512, 0, stream>>>(x, Fw, out, 768);

  k_local<<<256, 1024, 0, stream>>>(out, F, F + FE, Sbuf);

  // phases k=1..7: sq (F[k+3] <- F[k+2], fp32 ping-pong) || tree-up stage k
  for (int k = 1; k <= 7; ++k) {
    const int i = k + 3;  // chain index being produced
    const float* sqa = (i & 1) ? P2 : P1;   // fp32 of R^(2^(i-1))
    float* sqo = (i & 1) ? P1 : P2;
    const float* prin = (k == 1) ? Sbuf : Ub[k - 1];
    const int npr = (1 << (8 - k)) * 8;
    k_combo<<<128 + npr, 512, 0, stream>>>(sqa, F + (long)(i - 1) * FE, sqo,
                                           F + (long)i * FE, prin,
                                           F + (long)(k + 2) * FE, Ub[k]);
  }

  // down-sweep k=7..2 (k=1 fused into fix0); E1 lands in Ub[1], S stays in Sbuf
  k_down<<<8, 512, 0, stream>>>(h0, Ub[7], F + 10L * FE);
  for (int k = 7; k >= 2; --k)
    k_down<<<(1 << (8 - k)) * 8, 512, 0, stream>>>(Ub[k], Ub[k - 1], F + (long)(k + 2) * FE);

  k_fix0<<<256, 1024, 0, stream>>>(Ub[1], Sbuf, out, F, F + 3L * FE);
}

// Round 19
// 442.240 us; speedup vs baseline: 1.1329x; 1.0055x over previous
//
#include <hip/hip_runtime.h>
#include <hip/hip_bf16.h>

// Linear recurrence h_t = x_t@W + h_{t-1}@R, parallel scan, chunk C=8.
// R19 = R18 (444.7us) + three cuts:
//  1) fix0 odd-chunk entry step (E1@R^8+S): 2-term -> 1-term (chunk-local
//     injection, same safety class as fix0's 1-term steps)
//  2) dstep kk-unroll 2->4 (frag-load MLP; bit-identical)
//  3) tail k_xw merged into 3rd k_xwsq (one fewer launch)
// Per-CU-ingest model (~58 GB/s per CU at 16 waves): local at floor;
// fix0 paced by odd blocks; mid at launch-latency floor.

typedef float f32x4 __attribute__((ext_vector_type(4)));
typedef __bf16 bf16x8 __attribute__((ext_vector_type(8)));

#define TDIM 2048L
#define UDIM 512L
#define ST32 16384L     // elems per [32,512] state
#define ST64 32768L     // elems per [64,512] tile
#define TS 262144L      // elems per frag term
#define FE 786432L      // elems per 3-term frag matrix
#define PP 520          // padded plane row stride (bf16 elems)

__device__ __forceinline__ f32x4 mfma16(bf16x8 a, bf16x8 b, f32x4 c) {
  return __builtin_amdgcn_mfma_f32_16x16x32_bf16(a, b, c, 0, 0, 0);
}

// fp32 [32][512] swizzle (staging for sq/pair/down)
__device__ __forceinline__ int hidx(int row, int col) {
  return row * 512 + (col ^ ((row & 7) << 3));
}

__device__ __forceinline__ void pack8(const f32x4& v0, const f32x4& v1,
                                      bf16x8& hv, bf16x8& lv) {
#pragma unroll
  for (int j = 0; j < 4; ++j) {
    const float a = v0[j];
    const __bf16 ha = (__bf16)a;
    hv[j] = ha; lv[j] = (__bf16)(a - (float)ha);
    const float b = v1[j];
    const __bf16 hb = (__bf16)b;
    hv[j + 4] = hb; lv[j + 4] = (__bf16)(b - (float)hb);
  }
}

// ---- M=32 pair-plane helpers (stride PP, blockDim-stride loops) -----------

__device__ __forceinline__ void stage32p(const float* __restrict__ src,
                                         long pitch, __bf16* Phi, __bf16* Plo) {
  for (int i = threadIdx.x; i < 2048; i += blockDim.x) {
    const int row = i >> 6, cb = i & 63;
    const float* p = src + (long)row * pitch + cb * 8;
    bf16x8 hv, lv;
    pack8(*(const f32x4*)p, *(const f32x4*)(p + 4), hv, lv);
    const int o = row * PP + cb * 8;
    *(bf16x8*)(Phi + o) = hv;
    *(bf16x8*)(Plo + o) = lv;
  }
}

// planes -> out[B,T,U] at time t (fp32 = hi+lo), full-row coalesced stores
__device__ __forceinline__ void write_bt(const __bf16* Phi, const __bf16* Plo,
                                         float* out, long t) {
  for (int i = threadIdx.x; i < 2048; i += blockDim.x) {
    const int row = i >> 6, cb = i & 63;
    const int o = row * PP + cb * 8;
    const bf16x8 hv = *(const bf16x8*)(Phi + o);
    const bf16x8 lv = *(const bf16x8*)(Plo + o);
    f32x4 o0, o1;
#pragma unroll
    for (int j = 0; j < 4; ++j) {
      o0[j] = (float)hv[j] + (float)lv[j];
      o1[j] = (float)hv[j + 4] + (float)lv[j + 4];
    }
    float* dst = out + (long)row * (TDIM * UDIM) + t * UDIM + cb * 8;
    *(f32x4*)dst = o0;
    *(f32x4*)(dst + 4) = o1;
  }
}

__device__ __forceinline__ void write_flat(const __bf16* Phi, const __bf16* Plo,
                                           float* dst) {
  for (int i = threadIdx.x; i < 2048; i += blockDim.x) {
    const int row = i >> 6, cb = i & 63;
    const int o = row * PP + cb * 8;
    const bf16x8 hv = *(const bf16x8*)(Phi + o);
    const bf16x8 lv = *(const bf16x8*)(Plo + o);
    f32x4 o0, o1;
#pragma unroll
    for (int j = 0; j < 4; ++j) {
      o0[j] = (float)hv[j] + (float)lv[j];
      o1[j] = (float)hv[j + 4] + (float)lv[j + 4];
    }
    float* d = dst + row * 512 + cb * 8;
    *(f32x4*)d = o0;
    *(f32x4*)(d + 4) = o1;
  }
}

// One step on M=32 planes (1024 thr, 16 waves, wave owns 2 nt).
// <2,3>: a1b0,a1b1,a2b0.  <1,2>: a1b0,a2b0.
template <int NTERM, int NPROD, bool HAS_H>
__device__ __forceinline__ void pstep32(__bf16* Phi, __bf16* Plo,
                                        const __bf16* __restrict__ bfrag,
                                        const float* __restrict__ addbase,
                                        long addpitch) {
  const int tid = threadIdx.x, l = tid & 63, w = tid >> 6, g = l >> 4, li = l & 15;
  f32x4 addv[2][2];
#pragma unroll
  for (int mt = 0; mt < 2; ++mt)
#pragma unroll
    for (int q = 0; q < 2; ++q) {
      const int col = (w * 2 + q) * 16 + li;
#pragma unroll
      for (int r = 0; r < 4; ++r) {
        const int bat = mt * 16 + g * 4 + r;
        addv[mt][q][r] = addbase[(long)bat * addpitch + col];
      }
    }

  f32x4 acc[2][2] = {};
  if (HAS_H) {
#pragma unroll 4
    for (int kk = 0; kk < 16; ++kk) {
      bf16x8 b[NTERM][2];
#pragma unroll
      for (int q = 0; q < 2; ++q) {
        const long fo = (((long)(w * 2 + q) * 16 + kk) * 64 + l) * 8;
#pragma unroll
        for (int tt = 0; tt < NTERM; ++tt)
          b[tt][q] = *(const bf16x8*)(bfrag + (long)tt * TS + fo);
      }
#pragma unroll
      for (int mt = 0; mt < 2; ++mt) {
        const int o = (mt * 16 + li) * PP + kk * 32 + g * 8;
        const bf16x8 a1 = *(const bf16x8*)(Phi + o);
        const bf16x8 a2 = *(const bf16x8*)(Plo + o);
#pragma unroll
        for (int q = 0; q < 2; ++q) {
          acc[mt][q] = mfma16(a1, b[0][q], acc[mt][q]);
          if (NTERM >= 2) acc[mt][q] = mfma16(a1, b[1][q], acc[mt][q]);
          if (NPROD > NTERM) acc[mt][q] = mfma16(a2, b[0][q], acc[mt][q]);
          if (NPROD >= 4) acc[mt][q] = mfma16(a1, b[NTERM - 1][q], acc[mt][q]);
        }
      }
    }
    __syncthreads();  // plane reads done before overwrite
  }

#pragma unroll
  for (int mt = 0; mt < 2; ++mt)
#pragma unroll
    for (int q = 0; q < 2; ++q) {
      const int col = (w * 2 + q) * 16 + li;
#pragma unroll
      for (int r = 0; r < 4; ++r) {
        const float v = (HAS_H ? acc[mt][q][r] : 0.0f) + addv[mt][q][r];
        const int row = mt * 16 + g * 4 + r;
        const __bf16 hi = (__bf16)v;
        const int o = row * PP + col;
        Phi[o] = hi;
        Plo[o] = (__bf16)(v - (float)hi);
      }
    }
  __syncthreads();
}

// Double step: h <- h@R^2 + xw[t1]@R + xw[t2]; R lo-term dropped on xw path.
__device__ __forceinline__ void dstep(__bf16* Phi, __bf16* Plo,
                                      __bf16* Qhi, __bf16* Qlo,
                                      const __bf16* __restrict__ r2f,
                                      const __bf16* __restrict__ rf,
                                      const float* __restrict__ xw,
                                      long t1, long t2) {
  stage32p(xw + t1 * UDIM, TDIM * UDIM, Qhi, Qlo);
  __syncthreads();
  const int tid = threadIdx.x, l = tid & 63, w = tid >> 6, g = l >> 4, li = l & 15;
  f32x4 addv[2][2];
#pragma unroll
  for (int mt = 0; mt < 2; ++mt)
#pragma unroll
    for (int q = 0; q < 2; ++q) {
      const int col = (w * 2 + q) * 16 + li;
#pragma unroll
      for (int r = 0; r < 4; ++r) {
        const int bat = mt * 16 + g * 4 + r;
        addv[mt][q][r] = xw[(long)bat * (TDIM * UDIM) + t2 * UDIM + col];
      }
    }
  f32x4 acc[2][2] = {};
#pragma unroll 4
  for (int kk = 0; kk < 16; ++kk) {
    bf16x8 c0[2], c1[2], d0[2];
#pragma unroll
    for (int q = 0; q < 2; ++q) {
      const long fo = (((long)(w * 2 + q) * 16 + kk) * 64 + l) * 8;
      c0[q] = *(const bf16x8*)(r2f + fo);
      c1[q] = *(const bf16x8*)(r2f + TS + fo);
      d0[q] = *(const bf16x8*)(rf + fo);
    }
#pragma unroll
    for (int mt = 0; mt < 2; ++mt) {
      const int o = (mt * 16 + li) * PP + kk * 32 + g * 8;
      const bf16x8 h1 = *(const bf16x8*)(Phi + o);
      const bf16x8 h2 = *(const bf16x8*)(Plo + o);
      const bf16x8 q1 = *(const bf16x8*)(Qhi + o);
      const bf16x8 q2 = *(const bf16x8*)(Qlo + o);
#pragma unroll
      for (int q = 0; q < 2; ++q) {
        acc[mt][q] = mfma16(h1, c0[q], acc[mt][q]);
        acc[mt][q] = mfma16(q1, d0[q], acc[mt][q]);
        acc[mt][q] = mfma16(h1, c1[q], acc[mt][q]);
        acc[mt][q] = mfma16(h2, c0[q], acc[mt][q]);
        acc[mt][q] = mfma16(q2, d0[q], acc[mt][q]);
      }
    }
  }
  __syncthreads();
#pragma unroll
  for (int mt = 0; mt < 2; ++mt)
#pragma unroll
    for (int q = 0; q < 2; ++q) {
      const int col = (w * 2 + q) * 16 + li;
#pragma unroll
      for (int r = 0; r < 4; ++r) {
        const float v = acc[mt][q][r] + addv[mt][q][r];
        const int row = mt * 16 + g * 4 + r;
        const __bf16 hi = (__bf16)v;
        const int o = row * PP + col;
        Phi[o] = hi;
        Plo[o] = (__bf16)(v - (float)hi);
      }
    }
  __syncthreads();
}

// ---- device tasks ----------------------------------------------------------

// xW task, M=64: 512 thr = 8 waves; wave owns 4 nt; mt=0..3. W 1-term.
__device__ __forceinline__ void xw_dev(long blk, const float* __restrict__ x,
                                       const __bf16* __restrict__ wf,
                                       float* __restrict__ out, char* smem) {
  __bf16* Phi = (__bf16*)smem;  // [64][PP] hi-only = 66560 B
  const float* src = x + blk * ST64;
  for (int i = threadIdx.x; i < 4096; i += 512) {
    const int row = i >> 6, cb = i & 63;
    const f32x4 v0 = *(const f32x4*)(src + (long)row * 512 + cb * 8);
    const f32x4 v1 = *(const f32x4*)(src + (long)row * 512 + cb * 8 + 4);
    bf16x8 hv;
#pragma unroll
    for (int j = 0; j < 4; ++j) {
      hv[j] = (__bf16)v0[j];
      hv[j + 4] = (__bf16)v1[j];
    }
    *(bf16x8*)(Phi + row * PP + cb * 8) = hv;
  }
  __syncthreads();
  const int tid = threadIdx.x, l = tid & 63, w = tid >> 6, g = l >> 4, li = l & 15;
  f32x4 acc[4][4] = {};
#pragma unroll 4
  for (int kk = 0; kk < 16; ++kk) {
    bf16x8 b0[4];
#pragma unroll
    for (int q = 0; q < 4; ++q) {
      const long fo = (((long)(w * 4 + q) * 16 + kk) * 64 + l) * 8;
      b0[q] = *(const bf16x8*)(wf + fo);
    }
#pragma unroll
    for (int mt = 0; mt < 4; ++mt) {
      const bf16x8 a1 = *(const bf16x8*)(Phi + (mt * 16 + li) * PP + kk * 32 + g * 8);
#pragma unroll
      for (int q = 0; q < 4; ++q)
        acc[mt][q] = mfma16(a1, b0[q], acc[mt][q]);
    }
  }
  float* gdst = out + blk * ST64;
#pragma unroll
  for (int mt = 0; mt < 4; ++mt)
#pragma unroll
    for (int q = 0; q < 4; ++q) {
      const int col = (w * 4 + q) * 16 + li;
#pragma unroll
      for (int r = 0; r < 4; ++r)
        gdst[(long)(mt * 16 + g * 4 + r) * 512 + col] = acc[mt][q][r];
    }
}

// Stage a [32,512] fp32 state into swizzled LDS (512 thr).
__device__ __forceinline__ void stage_sw(const float* __restrict__ src,
                                         float* hbuf) {
  for (int i = threadIdx.x; i < 4096; i += 512) {
    const int flat = i * 4, row = flat >> 9, col = flat & 511;
    *(f32x4*)&hbuf[hidx(row, col)] = *(const f32x4*)&src[flat];
  }
}

// A @ Bfrag with A in swizzled LDS (2-term, 3 products).
__device__ __forceinline__ f32x4 lds_mm(const float* hbuf,
                                        const __bf16* __restrict__ bf,
                                        int mt, int ntg) {
  const int tid = threadIdx.x, l = tid & 63, g = (l >> 4) & 3, li = l & 15;
  f32x4 acc = {};
#pragma unroll 2
  for (int kk = 0; kk < 16; ++kk) {
    const long fo = (((long)ntg * 16 + kk) * 64 + l) * 8;
    const bf16x8 b0 = *(const bf16x8*)(bf + fo);
    const bf16x8 b1 = *(const bf16x8*)(bf + TS + fo);
    bf16x8 a1, a2;
    const float* pp = &hbuf[hidx(mt * 16 + li, kk * 32 + g * 8)];
#pragma unroll
    for (int j = 0; j < 8; ++j) {
      const float v = pp[j];
      const __bf16 hi = (__bf16)v;
      a1[j] = hi;
      a2[j] = (__bf16)(v - (float)hi);
    }
    acc = mfma16(a1, b0, acc);
    acc = mfma16(a1, b1, acc);
    acc = mfma16(a2, b0, acc);
  }
  return acc;
}

// Multiply task (128 blocks x 512 thr): out = A @ Bfrag, fp32 + frag split.
__device__ __forceinline__ void sq_dev(int b, const float* __restrict__ a,
                                       const __bf16* __restrict__ bf,
                                       float* __restrict__ of32,
                                       __bf16* __restrict__ ofr, float* hbuf) {
  const int rg = b >> 3, cg = b & 7;
  const int tid = threadIdx.x, l = tid & 63, w = tid >> 6, g = l >> 4, li = l & 15;
  stage_sw(a + (long)rg * ST32, hbuf);
  __syncthreads();
  const int mt = w >> 2, q = w & 3, ntg = cg * 4 + q;
  f32x4 acc = {};
#pragma unroll 2
  for (int kk = 0; kk < 16; ++kk) {
    const long fo = (((long)ntg * 16 + kk) * 64 + l) * 8;
    const bf16x8 b0 = *(const bf16x8*)(bf + fo);
    const bf16x8 b1 = *(const bf16x8*)(bf + TS + fo);
    const bf16x8 b2 = *(const bf16x8*)(bf + 2 * TS + fo);
    bf16x8 a1, a2;
    const float* pp = &hbuf[hidx(mt * 16 + li, kk * 32 + g * 8)];
#pragma unroll
    for (int j = 0; j < 8; ++j) {
      const float v = pp[j];
      const __bf16 hi = (__bf16)v;
      a1[j] = hi;
      a2[j] = (__bf16)(v - (float)hi);
    }
    acc = mfma16(a1, b0, acc);
    acc = mfma16(a1, b1, acc);
    acc = mfma16(a2, b0, acc);
    acc = mfma16(a1, b2, acc);
  }
  const int n = ntg * 16 + li;
#pragma unroll
  for (int r = 0; r < 4; ++r) {
    const int k = rg * 32 + mt * 16 + g * 4 + r;
    const float v = acc[r];
    of32[(long)k * 512 + n] = v;
    const __bf16 t1 = (__bf16)v;
    const float r1 = v - (float)t1;
    const __bf16 t2 = (__bf16)r1;
    const long fi = (((long)(n >> 4) * 16 + (k >> 5)) * 64 + ((k >> 3) & 3) * 16 + (n & 15)) * 8 + (k & 7);
    ofr[fi] = t1;
    ofr[TS + fi] = t2;
    ofr[2 * TS + fi] = (__bf16)(r1 - (float)t2);
  }
}

// Tree up-stage task (LDS-staged A): out[p] = in[2p] @ M + in[2p+1].
__device__ __forceinline__ void pair_dev(int b, const float* __restrict__ in,
                                         const __bf16* __restrict__ bf,
                                         float* __restrict__ outb, float* hbuf) {
  const int p = b >> 3, cs = b & 7;
  const int tid = threadIdx.x, l = tid & 63, w = tid >> 6, g = l >> 4, li = l & 15;
  stage_sw(in + (long)(2 * p) * ST32, hbuf);
  __syncthreads();
  const int mt = w >> 2, ntg = cs * 4 + (w & 3);
  const f32x4 acc = lds_mm(hbuf, bf, mt, ntg);
  const float* addp = in + (long)(2 * p + 1) * ST32;
  float* outp = outb + (long)p * ST32;
  const int col = ntg * 16 + li;
#pragma unroll
  for (int r = 0; r < 4; ++r) {
    const int row = mt * 16 + g * 4 + r;
    outp[(long)row * 512 + col] = acc[r] + addp[(long)row * 512 + col];
  }
}

// ---- kernels --------------------------------------------------------------

// Split two fp32 512x512 matrices into 3 bf16 terms (MFMA B-fragment order).
__global__ __launch_bounds__(512) void k_split2(const float* __restrict__ m0,
                                                const float* __restrict__ m1,
                                                __bf16* __restrict__ f0,
                                                __bf16* __restrict__ f1) {
  const int bb = blockIdx.x;
  const float* m = (bb < 512) ? m0 : m1;
  __bf16* f = (bb < 512) ? f0 : f1;
  const int idx = (bb & 511) * 512 + threadIdx.x;
  const int j = idx & 7, l = (idx >> 3) & 63, kk = (idx >> 9) & 15, nt = idx >> 13;
  const int k = kk * 32 + (l >> 4) * 8 + j;
  const int n = nt * 16 + (l & 15);
  const float v = m[k * 512 + n];
  const __bf16 t1 = (__bf16)v;
  const float r1 = v - (float)t1;
  const __bf16 t2 = (__bf16)r1;
  f[idx] = t1;
  f[TS + idx] = t2;
  f[2 * TS + idx] = (__bf16)(r1 - (float)t2);
}

// Co-dispatch: blocks 0-127 advance squaring chain; blocks 128+ do xw tiles.
__global__ __launch_bounds__(512) void k_xwsq(const float* __restrict__ sqa,
                                              const __bf16* __restrict__ sqbf,
                                              float* __restrict__ sqo32,
                                              __bf16* __restrict__ sqofr,
                                              const float* __restrict__ x,
                                              const __bf16* __restrict__ wf,
                                              float* __restrict__ out, int base) {
  __shared__ __align__(16) char smem[64 * PP * 2];
  const int b = blockIdx.x;
  if (b < 128)
    sq_dev(b, sqa, sqbf, sqo32, sqofr, (float*)smem);
  else
    xw_dev(base + (b - 128), x, wf, out, smem);
}

// Co-dispatch: blocks 0-127 squaring; blocks 128+ tree up-stage.
__global__ __launch_bounds__(512) void k_combo(const float* __restrict__ sqa,
                                               const __bf16* __restrict__ sqbf,
                                               float* __restrict__ sqo32,
                                               __bf16* __restrict__ sqofr,
                                               const float* __restrict__ prin,
                                               const __bf16* __restrict__ prbf,
                                               float* __restrict__ prout) {
  __shared__ float hbuf[ST32];
  const int b = blockIdx.x;
  if (b < 128)
    sq_dev(b, sqa, sqbf, sqo32, sqofr, hbuf);
  else
    pair_dev(b - 128, prin, prbf, prout, hbuf);
}

// Level-0 up-sweep: h = xw[t0]; 1 single step; 3 double steps. 2-term R.
__global__ __launch_bounds__(1024) void k_local(const float* __restrict__ xw,
                                                const __bf16* __restrict__ rf,
                                                const __bf16* __restrict__ r2f,
                                                float* __restrict__ sout) {
  __shared__ __bf16 Phi[32 * PP], Plo[32 * PP], Qhi[32 * PP], Qlo[32 * PP];
  const long c = blockIdx.x;
  stage32p(xw + c * 8 * UDIM, TDIM * UDIM, Phi, Plo);  // h = xw[t0]
  __syncthreads();
  pstep32<2, 3, true>(Phi, Plo, rf, xw + (c * 8 + 1) * UDIM, TDIM * UDIM);
  dstep(Phi, Plo, Qhi, Qlo, r2f, rf, xw, c * 8 + 2, c * 8 + 3);
  dstep(Phi, Plo, Qhi, Qlo, r2f, rf, xw, c * 8 + 4, c * 8 + 5);
  dstep(Phi, Plo, Qhi, Qlo, r2f, rf, xw, c * 8 + 6, c * 8 + 7);
  write_flat(Phi, Plo, sout + c * ST32);
}

// Final pass with fused down-k=1:
//   even chunk c=2p:  entry = E1[p]
//   odd  chunk c=2p+1: entry = E1[p]@R^8 + S[2p]   (1-term R^8)
// 8 serial 1-term-R steps; h written via planes + write_bt (coalesced).
__global__ __launch_bounds__(1024) void k_fix0(const float* __restrict__ e1,
                                               const float* __restrict__ sbuf,
                                               float* out,
                                               const __bf16* __restrict__ rf,
                                               const __bf16* __restrict__ r8f) {
  __shared__ __bf16 Phi[32 * PP], Plo[32 * PP];
  const long c = blockIdx.x;
  stage32p(e1 + (c >> 1) * ST32, 512, Phi, Plo);
  __syncthreads();
  if (c & 1)
    pstep32<1, 2, true>(Phi, Plo, r8f, sbuf + (c - 1) * ST32, 512);
  for (int j = 0; j < 8; ++j) {
    pstep32<1, 2, true>(Phi, Plo, rf, out + (c * 8 + j) * UDIM, TDIM * UDIM);
    write_bt(Phi, Plo, out, c * 8 + j);
  }
}

// Tree down-stage (LDS-staged parent), in place into child-level buffer:
//   ulev[2p+1] = epar[p] @ M + ulev[2p];  ulev[2p] = epar[p]
__global__ __launch_bounds__(512) void k_down(const float* __restrict__ epar,
                                              float* __restrict__ ulev,
                                              const __bf16* __restrict__ bf) {
  __shared__ float hbuf[ST32];
  const int p = blockIdx.x >> 3, cs = blockIdx.x & 7;
  const int tid = threadIdx.x, l = tid & 63, w = tid >> 6, g = l >> 4, li = l & 15;
  stage_sw(epar + (long)p * ST32, hbuf);
  __syncthreads();
  const int mt = w >> 2, ntg = cs * 4 + (w & 3);
  const f32x4 acc = lds_mm(hbuf, bf, mt, ntg);
  float* evp = ulev + (long)(2 * p) * ST32;
  float* outp = ulev + (long)(2 * p + 1) * ST32;
  const int col = ntg * 16 + li;
  float cp[4];
#pragma unroll
  for (int r = 0; r < 4; ++r) {
    const int row = mt * 16 + g * 4 + r;
    const long off = (long)row * 512 + col;
    cp[r] = hbuf[hidx(row, col)];     // = epar[p][row][col], exact
    outp[off] = acc[r] + evp[off];
  }
  __syncthreads();
#pragma unroll
  for (int r = 0; r < 4; ++r) {
    const int row = mt * 16 + g * 4 + r;
    evp[(long)row * 512 + col] = cp[r];
  }
}

extern "C" void kernel_launch(void* const* d_in, const int* in_sizes, int n_in,
                              void* d_out, int out_size, void* d_ws, size_t ws_size,
                              hipStream_t stream) {
  (void)in_sizes; (void)n_in; (void)out_size; (void)ws_size;
  const float* x  = (const float*)d_in[0];
  const float* W  = (const float*)d_in[1];
  const float* R  = (const float*)d_in[2];
  const float* h0 = (const float*)d_in[3];
  float* out = (float*)d_out;

  __bf16* F  = (__bf16*)d_ws;          // F[i] = frags of R^(2^i), i=0..10
  __bf16* Fw = F + 11 * FE;            // frags of W
  float* P1 = (float*)(Fw + FE);
  float* P2 = P1 + TS;
  float* Sbuf = P2 + TS;               // 256 chunk sums (S) -- preserved
  float* Ub[8];
  {
    float* up = Sbuf + 256 * ST32;
    for (int k = 1; k <= 7; ++k) { Ub[k] = up; up += (1L << (8 - k)) * ST32; }
  }

  k_split2<<<1024, 512, 0, stream>>>(W, R, Fw, F);

  // Head squarings co-dispatched with xw slices:
  //   F[1]=R^2 ; F[2]=R^4 ; F[3]=R^8  (fp32 ping-pong, frag split fused)
  // 3rd launch carries the remaining 512 xw tiles (R18's 4th launch merged).
  k_xwsq<<<384, 512, 0, stream>>>(R, F, P1, F + FE, x, Fw, out, 0);
  k_xwsq<<<384, 512, 0, stream>>>(P1, F + FE, P2, F + 2L * FE, x, Fw, out, 256);
  k_xwsq<<<640, 512, 0, stream>>>(P2, F + 2L * FE, P1, F + 3L * FE, x, Fw, out, 512);

  k_local<<<256, 1024, 0, stream>>>(out, F, F + FE, Sbuf);

  // phases k=1..7: sq (F[k+3] <- F[k+2], fp32 ping-pong) || tree-up stage k
  for (int k = 1; k <= 7; ++k) {
    const int i = k + 3;  // chain index being produced
    const float* sqa = (i & 1) ? P2 : P1;   // fp32 of R^(2^(i-1))
    float* sqo = (i & 1) ? P1 : P2;
    const float* prin = (k == 1) ? Sbuf : Ub[k - 1];
    const int npr = (1 << (8 - k)) * 8;
    k_combo<<<128 + npr, 512, 0, stream>>>(sqa, F + (long)(i - 1) * FE, sqo,
                                           F + (long)i * FE, prin,
                                           F + (long)(k + 2) * FE, Ub[k]);
  }

  // down-sweep k=7..2 (k=1 fused into fix0); E1 lands in Ub[1], S stays in Sbuf
  k_down<<<8, 512, 0, stream>>>(h0, Ub[7], F + 10L * FE);
  for (int k = 7; k >= 2; --k)
    k_down<<<(1 << (8 - k)) * 8, 512, 0, stream>>>(Ub[k], Ub[k - 1], F + (long)(k + 2) * FE);

  k_fix0<<<256, 1024, 0, stream>>>(Ub[1], Sbuf, out, F, F + 3L * FE);
}